// Round 2
// baseline (248.848 us; speedup 1.0000x reference)
//
#include <hip/hip_runtime.h>

#define VGRID 256
#define N_TAPS 27
#define CIN 64
#define COUT 64
#define BPTS 128   // points per block (2 groups of 16 per wave)

typedef short short8 __attribute__((ext_vector_type(8)));   // 8 bf16
typedef float float4v __attribute__((ext_vector_type(4)));  // MFMA C/D

__device__ __forceinline__ short f2bf(float x) {
    unsigned u = __builtin_bit_cast(unsigned, x);
    unsigned r = (u + 0x7FFF + ((u >> 16) & 1)) >> 16;  // RNE
    return (short)r;
}

// Table scatter (signed atomicMax beats 0xAA poison; no table init needed)
// + occupancy bitmap + fused weight conversion into FRAGMENT-MAJOR layout:
// Wt[tap][ks][quad][cout][8] so a B-fragment is one contiguous 16B load.
__global__ void __launch_bounds__(256) build_kernel(
        const int* __restrict__ coords, int* __restrict__ table,
        unsigned* __restrict__ bits, const float* __restrict__ W,
        short* __restrict__ Wt, int n, int bt_blocks) {
    if ((int)blockIdx.x >= bt_blocks) {
        int tap = blockIdx.x - bt_blocks;
        for (int e = threadIdx.x; e < CIN * COUT; e += 256) {
            int ci = e >> 6, co = e & 63;
            int ks = ci >> 5, quad = (ci >> 3) & 3, el = ci & 7;
            Wt[((((size_t)tap * 2 + ks) * 4 + quad) * 64 + co) * 8 + el] =
                f2bf(W[((size_t)tap * CIN + ci) * COUT + co]);
        }
        return;
    }
    int i = blockIdx.x * 256 + threadIdx.x;
    if (i >= n) return;
    int lin = (coords[i * 3 + 0] * VGRID + coords[i * 3 + 1]) * VGRID + coords[i * 3 + 2];
    atomicMax(&table[lin], i);   // last-write-wins == max index (ref semantics)
    atomicOr(&bits[lin >> 5], 1u << (lin & 31));
}

// Gather-formulation conv, occupancy-doubled: block=256 threads handles 128
// points; each wave computes 2 MFMA groups (32 points). Probe split across
// thread pairs (t, t+128): each half probes ~half the bitmap rows and
// prefetches 2 of 4 neighbor j's. Probe results handed off via LDS (direct
// broadcast reads in GEMM phase; no shuffles). Grid 2048 blocks -> 8/CU.
__global__ void __launch_bounds__(256, 8) fused_kernel(
        const int* __restrict__ coords, const int* __restrict__ table,
        const unsigned* __restrict__ bits, const float* __restrict__ feats,
        const short* __restrict__ Wt, float* __restrict__ out, int n) {
    __shared__ int s_pk[BPTS];
    __shared__ unsigned s_hm[2][BPTS];
    __shared__ int s_jc[BPTS];
    __shared__ int s_p[4][BPTS];

    int t = threadIdx.x;
    int p = t & (BPTS - 1);
    int h = t >> 7;                      // half: 0 or 1
    int i = blockIdx.x * BPTS + p;

    // ---- phase 1: split probe (h=0 rows 0-4, h=1 rows 5-8) ----
    int cx = 0, cy = 0, cz = 0;
    unsigned pmask = 0;
    if (i < n) {
        cx = coords[i * 3 + 0];
        cy = coords[i * 3 + 1];
        cz = coords[i * 3 + 2];
        if (h == 0) s_jc[p] = table[(cx * VGRID + cy) * VGRID + cz];

        int zlo = cz > 0 ? cz - 1 : 0;
        int zhi = cz < VGRID - 1 ? cz + 1 : VGRID - 1;
        int wlo = zlo >> 5, whi = zhi >> 5;
        unsigned rwa[5], rwb[5];
#pragma unroll
        for (int rr = 0; rr < 5; ++rr) {
            int r = h * 5 + rr;
            int nx = cx + r / 3 - 1, ny = cy + r % 3 - 1;
            bool v = (r < 9) && ((unsigned)nx < VGRID) && ((unsigned)ny < VGRID);
            int rb = ((nx * VGRID + ny) * VGRID) >> 5;  // row base word (row base %32==0)
            rwa[rr] = v ? bits[rb + wlo] : 0u;
            rwb[rr] = v ? bits[rb + whi] : 0u;
        }
#pragma unroll
        for (int rr = 0; rr < 5; ++rr) {
            int r = h * 5 + rr;
            if (r > 8) continue;  // compile-time per (h,rr)? no: runtime-guarded below
#pragma unroll
            for (int zz = 0; zz < 3; ++zz) {
                int k = r * 3 + zz;
                int nz = cz + zz - 1;
                if (r < 9 && k != 13 && (unsigned)nz < VGRID) {
                    unsigned wrd = ((nz >> 5) == wlo) ? rwa[rr] : rwb[rr];
                    pmask |= ((wrd >> (nz & 31)) & 1u) << k;
                }
            }
        }
    }
    if (h == 0) {
        s_pk[p] = (cx << 16) | (cy << 8) | cz;
        if (i >= n) s_jc[p] = 0;
    }
    s_hm[h][p] = pmask;
    __syncthreads();

    // ---- phase 2: combine masks; split j-prefetch (h: ranks 2h, 2h+1) ----
    {
        unsigned hmc = s_hm[0][p] | s_hm[1][p];
        if (h == 0) s_hm[0][p] = hmc;          // idempotent combine
        unsigned mm = hmc;
        if (h) { mm &= mm - 1u; if (mm) mm &= mm - 1u; }  // skip ranks 0,1
        int kA = -1, kB = -1;
        if (mm) { kA = __builtin_ctz(mm); mm &= mm - 1u;
                  if (mm) kB = __builtin_ctz(mm); }
        int ja = 0, jb = 0;
        if (kA >= 0)
            ja = table[((cx + kA / 9 - 1) * VGRID + (cy + (kA / 3) % 3 - 1)) * VGRID
                       + (cz + kA % 3 - 1)];
        if (kB >= 0)
            jb = table[((cx + kB / 9 - 1) * VGRID + (cy + (kB / 3) % 3 - 1)) * VGRID
                       + (cz + kB % 3 - 1)];
        s_p[2 * h + 0][p] = ja;
        s_p[2 * h + 1][p] = jb;
    }
    __syncthreads();

    // ---- phase 3: GEMM, 2 groups of 16 points per wave ----
    int wave = t >> 6, lane = t & 63;
    int m = lane & 15, quad = lane >> 4;
    const short8* Bp = (const short8*)Wt;
    int base = blockIdx.x * BPTS;

    for (int gg = 0; gg < 2; ++gg) {
        int g = wave * 2 + gg;
        int row = g * 16 + m;
        int rpk = s_pk[row];
        unsigned rhm = s_hm[0][row];
        int rjc = s_jc[row];
        int rp0 = s_p[0][row], rp1 = s_p[1][row];
        int rp2 = s_p[2][row], rp3 = s_p[3][row];

        unsigned gor = rhm;   // union over the 16 rows (quads hold same rows)
        gor |= (unsigned)__shfl_xor((int)gor, 1);
        gor |= (unsigned)__shfl_xor((int)gor, 2);
        gor |= (unsigned)__shfl_xor((int)gor, 4);
        gor |= (unsigned)__shfl_xor((int)gor, 8);
        gor = __builtin_amdgcn_readfirstlane(gor);

        float4v acc[4] = {{0,0,0,0},{0,0,0,0},{0,0,0,0},{0,0,0,0}};

        // center tap (13): A gathered straight to registers
        {
            const float* fr = feats + (size_t)rjc * CIN + quad * 8;
            float4 u0 = *(const float4*)(fr);
            float4 u1 = *(const float4*)(fr + 4);
            float4 v0 = *(const float4*)(fr + 32);
            float4 v1 = *(const float4*)(fr + 36);
            short8 a0 = {f2bf(u0.x), f2bf(u0.y), f2bf(u0.z), f2bf(u0.w),
                         f2bf(u1.x), f2bf(u1.y), f2bf(u1.z), f2bf(u1.w)};
            short8 a1 = {f2bf(v0.x), f2bf(v0.y), f2bf(v0.z), f2bf(v0.w),
                         f2bf(v1.x), f2bf(v1.y), f2bf(v1.z), f2bf(v1.w)};
#pragma unroll
            for (int nt = 0; nt < 4; ++nt) {
                short8 b0 = Bp[((13 * 2 + 0) * 4 + quad) * 64 + nt * 16 + m];
                short8 b1 = Bp[((13 * 2 + 1) * 4 + quad) * 64 + nt * 16 + m];
                acc[nt] = __builtin_amdgcn_mfma_f32_16x16x32_bf16(a0, b0, acc[nt], 0, 0, 0);
                acc[nt] = __builtin_amdgcn_mfma_f32_16x16x32_bf16(a1, b1, acc[nt], 0, 0, 0);
            }
        }

        // neighbor taps present anywhere in this 16-row group
        unsigned gm = gor;
        while (gm) {
            int k = (int)__builtin_ctz(gm); gm &= gm - 1u;
            bool has = (rhm >> k) & 1u;
            short8 h0 = {0,0,0,0,0,0,0,0}, h1 = {0,0,0,0,0,0,0,0};
            if (has) {
                int rank = __builtin_popcount(rhm & ((1u << k) - 1u));
                int j2;
                if (rank == 0) j2 = rp0;
                else if (rank == 1) j2 = rp1;
                else if (rank == 2) j2 = rp2;
                else if (rank == 3) j2 = rp3;
                else {
                    int rx = (rpk >> 16) & 255, ry = (rpk >> 8) & 255, rz = rpk & 255;
                    j2 = table[((rx + k / 9 - 1) * VGRID + (ry + (k / 3) % 3 - 1)) * VGRID
                               + (rz + k % 3 - 1)];
                }
                const float* hr = feats + (size_t)j2 * CIN + quad * 8;
                float4 u0 = *(const float4*)(hr);
                float4 u1 = *(const float4*)(hr + 4);
                float4 v0 = *(const float4*)(hr + 32);
                float4 v1 = *(const float4*)(hr + 36);
                h0 = (short8){f2bf(u0.x), f2bf(u0.y), f2bf(u0.z), f2bf(u0.w),
                              f2bf(u1.x), f2bf(u1.y), f2bf(u1.z), f2bf(u1.w)};
                h1 = (short8){f2bf(v0.x), f2bf(v0.y), f2bf(v0.z), f2bf(v0.w),
                              f2bf(v1.x), f2bf(v1.y), f2bf(v1.z), f2bf(v1.w)};
            }
#pragma unroll
            for (int nt = 0; nt < 4; ++nt) {
                short8 b0 = Bp[((k * 2 + 0) * 4 + quad) * 64 + nt * 16 + m];
                short8 b1 = Bp[((k * 2 + 1) * 4 + quad) * 64 + nt * 16 + m];
                acc[nt] = __builtin_amdgcn_mfma_f32_16x16x32_bf16(h0, b0, acc[nt], 0, 0, 0);
                acc[nt] = __builtin_amdgcn_mfma_f32_16x16x32_bf16(h1, b1, acc[nt], 0, 0, 0);
            }
        }

        // store 16x64 tile, written exactly once, non-atomic
#pragma unroll
        for (int nt = 0; nt < 4; ++nt)
#pragma unroll
            for (int r2 = 0; r2 < 4; ++r2) {
                int orow = base + g * 16 + quad * 4 + r2;
                if (orow < n) out[(size_t)orow * COUT + nt * 16 + m] = acc[nt][r2];
            }
    }
}

extern "C" void kernel_launch(void* const* d_in, const int* in_sizes, int n_in,
                              void* d_out, int out_size, void* d_ws, size_t ws_size,
                              hipStream_t stream) {
    const int* coords = (const int*)d_in[0];
    const float* feats = (const float*)d_in[1];
    const float* weights = (const float*)d_in[2];
    float* out = (float*)d_out;

    int n = in_sizes[0] / 3;  // 262144

    // workspace layout: bits @0 (2 MiB) | Wt @2 MiB (216 KiB) | table @4 MiB (64 MiB)
    char* ws = (char*)d_ws;
    size_t BITMAP_BYTES = (size_t)VGRID * VGRID * VGRID / 8;   // 2 MiB
    unsigned* bits = (unsigned*)ws;
    short* wbft = (short*)(ws + BITMAP_BYTES);
    int* table = (int*)(ws + ((size_t)4 << 20));               // never cleared

    // clear bitmap only; table: signed atomicMax beats 0xAA poison, and
    // probe reads only bitmap-set voxels (all written this launch)
    hipMemsetAsync(ws, 0, BITMAP_BYTES, stream);

    int bt_blocks = (n + 255) / 256;
    build_kernel<<<bt_blocks + N_TAPS, 256, 0, stream>>>(coords, table, bits,
                                                         weights, wbft, n, bt_blocks);

    int f_blocks = (n + BPTS - 1) / BPTS;
    fused_kernel<<<f_blocks, 256, 0, stream>>>(coords, table, bits, feats,
                                               wbft, out, n);
}

// Round 3
// 221.802 us; speedup vs baseline: 1.1219x; 1.1219x over previous
//
#include <hip/hip_runtime.h>

#define VGRID 256
#define N_TAPS 27
#define CIN 64
#define COUT 64
#define BPTS 128   // points per block (2 groups of 16 per wave)

typedef short short8 __attribute__((ext_vector_type(8)));   // 8 bf16
typedef float float4v __attribute__((ext_vector_type(4)));  // MFMA C/D

__device__ __forceinline__ short f2bf(float x) {
    unsigned u = __builtin_bit_cast(unsigned, x);
    unsigned r = (u + 0x7FFF + ((u >> 16) & 1)) >> 16;  // RNE
    return (short)r;
}

// Table scatter (signed atomicMax beats 0xAA poison; no table init needed)
// + occupancy bitmap + fused weight conversion into FRAGMENT-MAJOR layout:
// Wt[tap][ks][quad][cout][8] so a B-fragment is one contiguous 16B load.
__global__ void __launch_bounds__(256) build_kernel(
        const int* __restrict__ coords, int* __restrict__ table,
        unsigned* __restrict__ bits, const float* __restrict__ W,
        short* __restrict__ Wt, int n, int bt_blocks) {
    if ((int)blockIdx.x >= bt_blocks) {
        int tap = blockIdx.x - bt_blocks;
        for (int e = threadIdx.x; e < CIN * COUT; e += 256) {
            int ci = e >> 6, co = e & 63;
            int ks = ci >> 5, quad = (ci >> 3) & 3, el = ci & 7;
            Wt[((((size_t)tap * 2 + ks) * 4 + quad) * 64 + co) * 8 + el] =
                f2bf(W[((size_t)tap * CIN + ci) * COUT + co]);
        }
        return;
    }
    int i = blockIdx.x * 256 + threadIdx.x;
    if (i >= n) return;
    int lin = (coords[i * 3 + 0] * VGRID + coords[i * 3 + 1]) * VGRID + coords[i * 3 + 2];
    atomicMax(&table[lin], i);   // last-write-wins == max index (ref semantics)
    atomicOr(&bits[lin >> 5], 1u << (lin & 31));
}

// Gather-formulation conv: block=256 threads handles 128 points; each wave
// computes 2 MFMA groups (32 points). Probe split across thread pairs
// (t, t+128); results handed off via LDS. Grid 2048 blocks.
// NOTE: no min-waves clamp — round-1's (256,8) forced VGPR=32 and spilled
// the accumulators to scratch (+92 MB/iter traffic). Compiler at ~56 VGPR
// supports 8 waves/SIMD on its own.
__global__ void __launch_bounds__(256) fused_kernel(
        const int* __restrict__ coords, const int* __restrict__ table,
        const unsigned* __restrict__ bits, const float* __restrict__ feats,
        const short* __restrict__ Wt, float* __restrict__ out, int n) {
    __shared__ int s_pk[BPTS];
    __shared__ unsigned s_hm[2][BPTS];
    __shared__ int s_jc[BPTS];
    __shared__ int s_p[4][BPTS];

    int t = threadIdx.x;
    int p = t & (BPTS - 1);
    int h = t >> 7;                      // half: 0 or 1
    int i = blockIdx.x * BPTS + p;

    // ---- phase 1: split probe (h=0 rows 0-4, h=1 rows 5-8) ----
    int cx = 0, cy = 0, cz = 0;
    unsigned pmask = 0;
    if (i < n) {
        cx = coords[i * 3 + 0];
        cy = coords[i * 3 + 1];
        cz = coords[i * 3 + 2];
        if (h == 0) s_jc[p] = table[(cx * VGRID + cy) * VGRID + cz];

        int zlo = cz > 0 ? cz - 1 : 0;
        int zhi = cz < VGRID - 1 ? cz + 1 : VGRID - 1;
        int wlo = zlo >> 5, whi = zhi >> 5;
        unsigned rwa[5], rwb[5];
#pragma unroll
        for (int rr = 0; rr < 5; ++rr) {
            int r = h * 5 + rr;
            int nx = cx + r / 3 - 1, ny = cy + r % 3 - 1;
            bool v = (r < 9) && ((unsigned)nx < VGRID) && ((unsigned)ny < VGRID);
            int rb = ((nx * VGRID + ny) * VGRID) >> 5;  // row base word (row base %32==0)
            rwa[rr] = v ? bits[rb + wlo] : 0u;
            rwb[rr] = v ? bits[rb + whi] : 0u;
        }
#pragma unroll
        for (int rr = 0; rr < 5; ++rr) {
            int r = h * 5 + rr;
#pragma unroll
            for (int zz = 0; zz < 3; ++zz) {
                int k = r * 3 + zz;
                int nz = cz + zz - 1;
                if (r < 9 && k != 13 && (unsigned)nz < VGRID) {
                    unsigned wrd = ((nz >> 5) == wlo) ? rwa[rr] : rwb[rr];
                    pmask |= ((wrd >> (nz & 31)) & 1u) << k;
                }
            }
        }
    }
    if (h == 0) {
        s_pk[p] = (cx << 16) | (cy << 8) | cz;
        if (i >= n) s_jc[p] = 0;
    }
    s_hm[h][p] = pmask;
    __syncthreads();

    // ---- phase 2: combine masks; split j-prefetch (h: ranks 2h, 2h+1) ----
    {
        unsigned hmc = s_hm[0][p] | s_hm[1][p];
        if (h == 0) s_hm[0][p] = hmc;          // idempotent combine
        unsigned mm = hmc;
        if (h) { mm &= mm - 1u; if (mm) mm &= mm - 1u; }  // skip ranks 0,1
        int kA = -1, kB = -1;
        if (mm) { kA = __builtin_ctz(mm); mm &= mm - 1u;
                  if (mm) kB = __builtin_ctz(mm); }
        int ja = 0, jb = 0;
        if (kA >= 0)
            ja = table[((cx + kA / 9 - 1) * VGRID + (cy + (kA / 3) % 3 - 1)) * VGRID
                       + (cz + kA % 3 - 1)];
        if (kB >= 0)
            jb = table[((cx + kB / 9 - 1) * VGRID + (cy + (kB / 3) % 3 - 1)) * VGRID
                       + (cz + kB % 3 - 1)];
        s_p[2 * h + 0][p] = ja;
        s_p[2 * h + 1][p] = jb;
    }
    __syncthreads();

    // ---- phase 3: GEMM, 2 groups of 16 points per wave ----
    int wave = t >> 6, lane = t & 63;
    int m = lane & 15, quad = lane >> 4;
    const short8* Bp = (const short8*)Wt;
    int base = blockIdx.x * BPTS;

    for (int gg = 0; gg < 2; ++gg) {
        int g = wave * 2 + gg;
        int row = g * 16 + m;
        int rpk = s_pk[row];
        unsigned rhm = s_hm[0][row];
        int rjc = s_jc[row];
        int rp0 = s_p[0][row], rp1 = s_p[1][row];
        int rp2 = s_p[2][row], rp3 = s_p[3][row];

        unsigned gor = rhm;   // union over the 16 rows (quads hold same rows)
        gor |= (unsigned)__shfl_xor((int)gor, 1);
        gor |= (unsigned)__shfl_xor((int)gor, 2);
        gor |= (unsigned)__shfl_xor((int)gor, 4);
        gor |= (unsigned)__shfl_xor((int)gor, 8);
        gor = __builtin_amdgcn_readfirstlane(gor);

        float4v acc[4] = {{0,0,0,0},{0,0,0,0},{0,0,0,0},{0,0,0,0}};

        // center tap (13): A gathered straight to registers
        {
            const float* fr = feats + (size_t)rjc * CIN + quad * 8;
            float4 u0 = *(const float4*)(fr);
            float4 u1 = *(const float4*)(fr + 4);
            float4 v0 = *(const float4*)(fr + 32);
            float4 v1 = *(const float4*)(fr + 36);
            short8 a0 = {f2bf(u0.x), f2bf(u0.y), f2bf(u0.z), f2bf(u0.w),
                         f2bf(u1.x), f2bf(u1.y), f2bf(u1.z), f2bf(u1.w)};
            short8 a1 = {f2bf(v0.x), f2bf(v0.y), f2bf(v0.z), f2bf(v0.w),
                         f2bf(v1.x), f2bf(v1.y), f2bf(v1.z), f2bf(v1.w)};
#pragma unroll
            for (int nt = 0; nt < 4; ++nt) {
                short8 b0 = Bp[((13 * 2 + 0) * 4 + quad) * 64 + nt * 16 + m];
                short8 b1 = Bp[((13 * 2 + 1) * 4 + quad) * 64 + nt * 16 + m];
                acc[nt] = __builtin_amdgcn_mfma_f32_16x16x32_bf16(a0, b0, acc[nt], 0, 0, 0);
                acc[nt] = __builtin_amdgcn_mfma_f32_16x16x32_bf16(a1, b1, acc[nt], 0, 0, 0);
            }
        }

        // neighbor taps present anywhere in this 16-row group
        unsigned gm = gor;
        while (gm) {
            int k = (int)__builtin_ctz(gm); gm &= gm - 1u;
            bool has = (rhm >> k) & 1u;
            short8 h0 = {0,0,0,0,0,0,0,0}, h1 = {0,0,0,0,0,0,0,0};
            if (has) {
                int rank = __builtin_popcount(rhm & ((1u << k) - 1u));
                int j2;
                if (rank == 0) j2 = rp0;
                else if (rank == 1) j2 = rp1;
                else if (rank == 2) j2 = rp2;
                else if (rank == 3) j2 = rp3;
                else {
                    int rx = (rpk >> 16) & 255, ry = (rpk >> 8) & 255, rz = rpk & 255;
                    j2 = table[((rx + k / 9 - 1) * VGRID + (ry + (k / 3) % 3 - 1)) * VGRID
                               + (rz + k % 3 - 1)];
                }
                const float* hr = feats + (size_t)j2 * CIN + quad * 8;
                float4 u0 = *(const float4*)(hr);
                float4 u1 = *(const float4*)(hr + 4);
                float4 v0 = *(const float4*)(hr + 32);
                float4 v1 = *(const float4*)(hr + 36);
                h0 = (short8){f2bf(u0.x), f2bf(u0.y), f2bf(u0.z), f2bf(u0.w),
                              f2bf(u1.x), f2bf(u1.y), f2bf(u1.z), f2bf(u1.w)};
                h1 = (short8){f2bf(v0.x), f2bf(v0.y), f2bf(v0.z), f2bf(v0.w),
                              f2bf(v1.x), f2bf(v1.y), f2bf(v1.z), f2bf(v1.w)};
            }
#pragma unroll
            for (int nt = 0; nt < 4; ++nt) {
                short8 b0 = Bp[((k * 2 + 0) * 4 + quad) * 64 + nt * 16 + m];
                short8 b1 = Bp[((k * 2 + 1) * 4 + quad) * 64 + nt * 16 + m];
                acc[nt] = __builtin_amdgcn_mfma_f32_16x16x32_bf16(h0, b0, acc[nt], 0, 0, 0);
                acc[nt] = __builtin_amdgcn_mfma_f32_16x16x32_bf16(h1, b1, acc[nt], 0, 0, 0);
            }
        }

        // store 16x64 tile, written exactly once, non-atomic
#pragma unroll
        for (int nt = 0; nt < 4; ++nt)
#pragma unroll
            for (int r2 = 0; r2 < 4; ++r2) {
                int orow = base + g * 16 + quad * 4 + r2;
                if (orow < n) out[(size_t)orow * COUT + nt * 16 + m] = acc[nt][r2];
            }
    }
}

extern "C" void kernel_launch(void* const* d_in, const int* in_sizes, int n_in,
                              void* d_out, int out_size, void* d_ws, size_t ws_size,
                              hipStream_t stream) {
    const int* coords = (const int*)d_in[0];
    const float* feats = (const float*)d_in[1];
    const float* weights = (const float*)d_in[2];
    float* out = (float*)d_out;

    int n = in_sizes[0] / 3;  // 262144

    // workspace layout: bits @0 (2 MiB) | Wt @2 MiB (216 KiB) | table @4 MiB (64 MiB)
    char* ws = (char*)d_ws;
    size_t BITMAP_BYTES = (size_t)VGRID * VGRID * VGRID / 8;   // 2 MiB
    unsigned* bits = (unsigned*)ws;
    short* wbft = (short*)(ws + BITMAP_BYTES);
    int* table = (int*)(ws + ((size_t)4 << 20));               // never cleared

    // clear bitmap only; table: signed atomicMax beats 0xAA poison, and
    // probe reads only bitmap-set voxels (all written this launch)
    hipMemsetAsync(ws, 0, BITMAP_BYTES, stream);

    int bt_blocks = (n + 255) / 256;
    build_kernel<<<bt_blocks + N_TAPS, 256, 0, stream>>>(coords, table, bits,
                                                         weights, wbft, n, bt_blocks);

    int f_blocks = (n + BPTS - 1) / BPTS;
    fused_kernel<<<f_blocks, 256, 0, stream>>>(coords, table, bits, feats,
                                               wbft, out, n);
}

// Round 5
// 209.529 us; speedup vs baseline: 1.1877x; 1.0586x over previous
//
#include <hip/hip_runtime.h>

#define VGRID 256
#define N_TAPS 27
#define CIN 64
#define COUT 64
#define BPTS 128   // points per block (2 groups of 16 per wave)

typedef short short8 __attribute__((ext_vector_type(8)));   // 8 bf16
typedef float float4v __attribute__((ext_vector_type(4)));  // MFMA C/D + NT loads

__device__ __forceinline__ short f2bf(float x) {
    unsigned u = __builtin_bit_cast(unsigned, x);
    unsigned r = (u + 0x7FFF + ((u >> 16) & 1)) >> 16;  // RNE
    return (short)r;
}

// blocks [0,bt): table scatter + bitmap
// blocks [bt, bt+27): weight conversion to fragment-major bf16
// blocks [bt+27, ...): feats f32 -> bf16 streaming convert (nontemporal src)
__global__ void __launch_bounds__(256) build_kernel(
        const int* __restrict__ coords, int* __restrict__ table,
        unsigned* __restrict__ bits, const float* __restrict__ W,
        short* __restrict__ Wt, const float* __restrict__ F,
        short* __restrict__ Fb, int n, int bt_blocks, int fb_elems) {
    int b = (int)blockIdx.x;
    if (b >= bt_blocks + N_TAPS) {
        int idx = (b - bt_blocks - N_TAPS) * 256 + (int)threadIdx.x;
        int e = idx * 8;
        if (e < fb_elems) {
            const float4v* s = (const float4v*)(F + e);
            float4v x = __builtin_nontemporal_load(s);
            float4v y = __builtin_nontemporal_load(s + 1);
            short8 o = {f2bf(x[0]), f2bf(x[1]), f2bf(x[2]), f2bf(x[3]),
                        f2bf(y[0]), f2bf(y[1]), f2bf(y[2]), f2bf(y[3])};
            *(short8*)(Fb + e) = o;
        }
        return;
    }
    if (b >= bt_blocks) {
        int tap = b - bt_blocks;
        for (int e = threadIdx.x; e < CIN * COUT; e += 256) {
            int ci = e >> 6, co = e & 63;
            int ks = ci >> 5, quad = (ci >> 3) & 3, el = ci & 7;
            Wt[((((size_t)tap * 2 + ks) * 4 + quad) * 64 + co) * 8 + el] =
                f2bf(W[((size_t)tap * CIN + ci) * COUT + co]);
        }
        return;
    }
    int i = b * 256 + threadIdx.x;
    if (i >= n) return;
    int lin = (coords[i * 3 + 0] * VGRID + coords[i * 3 + 1]) * VGRID + coords[i * 3 + 2];
    atomicMax(&table[lin], i);   // last-write-wins == max index (ref semantics)
    atomicOr(&bits[lin >> 5], 1u << (lin & 31));
}

// Gather-formulation conv: block=256 threads handles 128 points; each wave
// computes 2 MFMA groups (32 points). Probe split across thread pairs
// (t, t+128); results handed off via LDS. Grid 2048 blocks.
// BF=true: A-fragments loaded directly from pre-converted bf16 feats
// (halved gather bytes, no f32 staging regs/cvts in the hot loop).
// No min-waves clamp (round-1 lesson: forcing 8 spilled acc to scratch).
template<bool BF>
__global__ void __launch_bounds__(256) fused_kernel_t(
        const int* __restrict__ coords, const int* __restrict__ table,
        const unsigned* __restrict__ bits, const float* __restrict__ feats,
        const short* __restrict__ featsb, const short* __restrict__ Wt,
        float* __restrict__ out, int n) {
    __shared__ int s_pk[BPTS];
    __shared__ unsigned s_hm[2][BPTS];
    __shared__ int s_jc[BPTS];
    __shared__ int s_p[4][BPTS];

    int t = threadIdx.x;
    int p = t & (BPTS - 1);
    int h = t >> 7;                      // half: 0 or 1
    int i = blockIdx.x * BPTS + p;

    // ---- phase 1: split probe (h=0 rows 0-4, h=1 rows 5-8) ----
    int cx = 0, cy = 0, cz = 0;
    unsigned pmask = 0;
    if (i < n) {
        cx = coords[i * 3 + 0];
        cy = coords[i * 3 + 1];
        cz = coords[i * 3 + 2];
        if (h == 0) s_jc[p] = table[(cx * VGRID + cy) * VGRID + cz];

        int zlo = cz > 0 ? cz - 1 : 0;
        int zhi = cz < VGRID - 1 ? cz + 1 : VGRID - 1;
        int wlo = zlo >> 5, whi = zhi >> 5;
        unsigned rwa[5], rwb[5];
#pragma unroll
        for (int rr = 0; rr < 5; ++rr) {
            int r = h * 5 + rr;
            int nx = cx + r / 3 - 1, ny = cy + r % 3 - 1;
            bool v = (r < 9) && ((unsigned)nx < VGRID) && ((unsigned)ny < VGRID);
            int rb = ((nx * VGRID + ny) * VGRID) >> 5;  // row base word (base %32==0)
            rwa[rr] = v ? bits[rb + wlo] : 0u;
            rwb[rr] = v ? bits[rb + whi] : 0u;
        }
#pragma unroll
        for (int rr = 0; rr < 5; ++rr) {
            int r = h * 5 + rr;
#pragma unroll
            for (int zz = 0; zz < 3; ++zz) {
                int k = r * 3 + zz;
                int nz = cz + zz - 1;
                if (r < 9 && k != 13 && (unsigned)nz < VGRID) {
                    unsigned wrd = ((nz >> 5) == wlo) ? rwa[rr] : rwb[rr];
                    pmask |= ((wrd >> (nz & 31)) & 1u) << k;
                }
            }
        }
    }
    if (h == 0) {
        s_pk[p] = (cx << 16) | (cy << 8) | cz;
        if (i >= n) s_jc[p] = 0;
    }
    s_hm[h][p] = pmask;
    __syncthreads();

    // ---- phase 2: combine masks; split j-prefetch (h: ranks 2h, 2h+1) ----
    {
        unsigned hmc = s_hm[0][p] | s_hm[1][p];
        if (h == 0) s_hm[0][p] = hmc;          // idempotent combine
        unsigned mm = hmc;
        if (h) { mm &= mm - 1u; if (mm) mm &= mm - 1u; }  // skip ranks 0,1
        int kA = -1, kB = -1;
        if (mm) { kA = __builtin_ctz(mm); mm &= mm - 1u;
                  if (mm) kB = __builtin_ctz(mm); }
        int ja = 0, jb = 0;
        if (kA >= 0)
            ja = table[((cx + kA / 9 - 1) * VGRID + (cy + (kA / 3) % 3 - 1)) * VGRID
                       + (cz + kA % 3 - 1)];
        if (kB >= 0)
            jb = table[((cx + kB / 9 - 1) * VGRID + (cy + (kB / 3) % 3 - 1)) * VGRID
                       + (cz + kB % 3 - 1)];
        s_p[2 * h + 0][p] = ja;
        s_p[2 * h + 1][p] = jb;
    }
    __syncthreads();

    // ---- phase 3: GEMM, 2 groups of 16 points per wave ----
    int wave = t >> 6, lane = t & 63;
    int m = lane & 15, quad = lane >> 4;
    const short8* Bp = (const short8*)Wt;
    const short8* Fp = (const short8*)featsb;   // 16B units; row j = 8 units
    int base = blockIdx.x * BPTS;

    for (int gg = 0; gg < 2; ++gg) {
        int g = wave * 2 + gg;
        int row = g * 16 + m;
        unsigned rhm = s_hm[0][row];

        unsigned gor = rhm;   // union over the 16 rows (quads hold same rows)
        gor |= (unsigned)__shfl_xor((int)gor, 1);
        gor |= (unsigned)__shfl_xor((int)gor, 2);
        gor |= (unsigned)__shfl_xor((int)gor, 4);
        gor |= (unsigned)__shfl_xor((int)gor, 8);
        gor = __builtin_amdgcn_readfirstlane(gor);

        float4v acc[4] = {{0,0,0,0},{0,0,0,0},{0,0,0,0},{0,0,0,0}};

        // center tap (13): A gathered straight to registers
        {
            int rjc = s_jc[row];
            short8 a0, a1;
            if constexpr (BF) {
                a0 = Fp[(size_t)rjc * 8 + quad];
                a1 = Fp[(size_t)rjc * 8 + 4 + quad];
            } else {
                const float* fr = feats + (size_t)rjc * CIN + quad * 8;
                float4v u0 = *(const float4v*)(fr);
                float4v u1 = *(const float4v*)(fr + 4);
                float4v v0 = *(const float4v*)(fr + 32);
                float4v v1 = *(const float4v*)(fr + 36);
                a0 = (short8){f2bf(u0[0]), f2bf(u0[1]), f2bf(u0[2]), f2bf(u0[3]),
                              f2bf(u1[0]), f2bf(u1[1]), f2bf(u1[2]), f2bf(u1[3])};
                a1 = (short8){f2bf(v0[0]), f2bf(v0[1]), f2bf(v0[2]), f2bf(v0[3]),
                              f2bf(v1[0]), f2bf(v1[1]), f2bf(v1[2]), f2bf(v1[3])};
            }
#pragma unroll
            for (int nt = 0; nt < 4; ++nt) {
                short8 b0 = Bp[((13 * 2 + 0) * 4 + quad) * 64 + nt * 16 + m];
                short8 b1 = Bp[((13 * 2 + 1) * 4 + quad) * 64 + nt * 16 + m];
                acc[nt] = __builtin_amdgcn_mfma_f32_16x16x32_bf16(a0, b0, acc[nt], 0, 0, 0);
                acc[nt] = __builtin_amdgcn_mfma_f32_16x16x32_bf16(a1, b1, acc[nt], 0, 0, 0);
            }
        }

        // neighbor taps present anywhere in this 16-row group
        unsigned gm = gor;
        while (gm) {
            int k = (int)__builtin_ctz(gm); gm &= gm - 1u;
            bool has = (rhm >> k) & 1u;
            short8 h0 = {0,0,0,0,0,0,0,0}, h1 = {0,0,0,0,0,0,0,0};
            if (has) {
                int rank = __builtin_popcount(rhm & ((1u << k) - 1u));
                int j2;
                if (rank < 4) {
                    j2 = s_p[rank][row];           // dynamic LDS index, not regs
                } else {
                    int rpk = s_pk[row];
                    int rx = (rpk >> 16) & 255, ry = (rpk >> 8) & 255, rz = rpk & 255;
                    j2 = table[((rx + k / 9 - 1) * VGRID + (ry + (k / 3) % 3 - 1)) * VGRID
                               + (rz + k % 3 - 1)];
                }
                if constexpr (BF) {
                    h0 = Fp[(size_t)j2 * 8 + quad];
                    h1 = Fp[(size_t)j2 * 8 + 4 + quad];
                } else {
                    const float* hr = feats + (size_t)j2 * CIN + quad * 8;
                    float4v u0 = *(const float4v*)(hr);
                    float4v u1 = *(const float4v*)(hr + 4);
                    float4v v0 = *(const float4v*)(hr + 32);
                    float4v v1 = *(const float4v*)(hr + 36);
                    h0 = (short8){f2bf(u0[0]), f2bf(u0[1]), f2bf(u0[2]), f2bf(u0[3]),
                                  f2bf(u1[0]), f2bf(u1[1]), f2bf(u1[2]), f2bf(u1[3])};
                    h1 = (short8){f2bf(v0[0]), f2bf(v0[1]), f2bf(v0[2]), f2bf(v0[3]),
                                  f2bf(v1[0]), f2bf(v1[1]), f2bf(v1[2]), f2bf(v1[3])};
                }
            }
#pragma unroll
            for (int nt = 0; nt < 4; ++nt) {
                short8 b0 = Bp[((k * 2 + 0) * 4 + quad) * 64 + nt * 16 + m];
                short8 b1 = Bp[((k * 2 + 1) * 4 + quad) * 64 + nt * 16 + m];
                acc[nt] = __builtin_amdgcn_mfma_f32_16x16x32_bf16(h0, b0, acc[nt], 0, 0, 0);
                acc[nt] = __builtin_amdgcn_mfma_f32_16x16x32_bf16(h1, b1, acc[nt], 0, 0, 0);
            }
        }

        // store 16x64 tile, written exactly once; nontemporal (never re-read,
        // keeps L3 for the bf16 gather set)
#pragma unroll
        for (int nt = 0; nt < 4; ++nt)
#pragma unroll
            for (int r2 = 0; r2 < 4; ++r2) {
                int orow = base + g * 16 + quad * 4 + r2;
                if (orow < n)
                    __builtin_nontemporal_store(
                        acc[nt][r2], &out[(size_t)orow * COUT + nt * 16 + m]);
            }
    }
}

extern "C" void kernel_launch(void* const* d_in, const int* in_sizes, int n_in,
                              void* d_out, int out_size, void* d_ws, size_t ws_size,
                              hipStream_t stream) {
    const int* coords = (const int*)d_in[0];
    const float* feats = (const float*)d_in[1];
    const float* weights = (const float*)d_in[2];
    float* out = (float*)d_out;

    int n = in_sizes[0] / 3;  // 262144

    // preferred layout: bits @0 (2MiB) | Wt @2MiB | feats_bf @4MiB (32MiB)
    //                   | table @36MiB (64MiB)  => 100MiB
    // fallback (small ws): bits @0 | Wt @2MiB | table @4MiB => 68MiB
    char* ws = (char*)d_ws;
    size_t BITMAP_BYTES = (size_t)VGRID * VGRID * VGRID / 8;   // 2 MiB
    bool bf = ws_size >= ((size_t)100 << 20);
    unsigned* bits = (unsigned*)ws;
    short* wbft = (short*)(ws + BITMAP_BYTES);
    short* fb = bf ? (short*)(ws + ((size_t)4 << 20)) : nullptr;
    int* table = (int*)(ws + (bf ? ((size_t)36 << 20) : ((size_t)4 << 20)));

    // clear bitmap only; table: signed atomicMax beats 0xAA poison, and
    // probe reads only bitmap-set voxels (all written this launch)
    hipMemsetAsync(ws, 0, BITMAP_BYTES, stream);

    int bt_blocks = (n + 255) / 256;
    int fb_elems = bf ? n * CIN : 0;
    int conv_blocks = bf ? (fb_elems / 8 + 255) / 256 : 0;
    build_kernel<<<bt_blocks + N_TAPS + conv_blocks, 256, 0, stream>>>(
        coords, table, bits, weights, wbft, feats, fb, n, bt_blocks, fb_elems);

    int f_blocks = (n + BPTS - 1) / BPTS;
    if (bf)
        fused_kernel_t<true><<<f_blocks, 256, 0, stream>>>(
            coords, table, bits, feats, fb, wbft, out, n);
    else
        fused_kernel_t<false><<<f_blocks, 256, 0, stream>>>(
            coords, table, bits, feats, fb, wbft, out, n);
}